// Round 1
// baseline (1071.849 us; speedup 1.0000x reference)
//
#include <hip/hip_runtime.h>

#define NN 50000
#define NE 800000
#define IND 768
#define CH  128   // output channels per node for both layers

// ---------------- GEMM: C[M x 128] = A[M x K] * B[K x 128], fp32 ----------------
#define BM 64
#define BN 128
#define BK 16

__global__ __launch_bounds__(256) void gemm_f32(
    const float* __restrict__ A, const float* __restrict__ B,
    float* __restrict__ C, int M, int K)
{
    __shared__ float As[BK][BM + 4];   // transposed tile, padded (align16 + conflict)
    __shared__ float Bs[BK][BN];

    const int tid = threadIdx.x;
    const int tx = tid & 15;          // n-group: 8 cols
    const int ty = tid >> 4;          // m-group: 4 rows
    const int m0 = blockIdx.x * BM;

    const int arow = tid >> 2;        // 0..63
    const int akc  = (tid & 3) * 4;   // 0,4,8,12

    float acc[4][8];
    #pragma unroll
    for (int i = 0; i < 4; ++i)
        #pragma unroll
        for (int j = 0; j < 8; ++j) acc[i][j] = 0.f;

    for (int k0 = 0; k0 < K; k0 += BK) {
        // load A tile (64 rows x 16 k), one float4 per thread
        {
            const int ar = m0 + arow;
            float4 av = make_float4(0.f, 0.f, 0.f, 0.f);
            if (ar < M) av = *(const float4*)&A[(size_t)ar * K + k0 + akc];
            As[akc + 0][arow] = av.x;
            As[akc + 1][arow] = av.y;
            As[akc + 2][arow] = av.z;
            As[akc + 3][arow] = av.w;
        }
        // load B tile (16 x 128), two float4 per thread, contiguous per wave
        #pragma unroll
        for (int j = 0; j < 2; ++j) {
            const int f = j * 256 + tid;        // 0..511 float4 index
            const int br = f >> 5;              // 0..15
            const int bc = (f & 31) * 4;        // 0..124
            *(float4*)&Bs[br][bc] = *(const float4*)&B[(size_t)(k0 + br) * BN + bc];
        }
        __syncthreads();

        #pragma unroll
        for (int k = 0; k < BK; ++k) {
            const float4 a4 = *(const float4*)&As[k][ty * 4];
            const float4 b0 = *(const float4*)&Bs[k][tx * 8];
            const float4 b1 = *(const float4*)&Bs[k][tx * 8 + 4];
            const float av[4] = {a4.x, a4.y, a4.z, a4.w};
            const float bv[8] = {b0.x, b0.y, b0.z, b0.w, b1.x, b1.y, b1.z, b1.w};
            #pragma unroll
            for (int i = 0; i < 4; ++i)
                #pragma unroll
                for (int j = 0; j < 8; ++j)
                    acc[i][j] = fmaf(av[i], bv[j], acc[i][j]);
        }
        __syncthreads();
    }

    #pragma unroll
    for (int i = 0; i < 4; ++i) {
        const int row = m0 + ty * 4 + i;
        if (row < M) {
            float4 v0 = make_float4(acc[i][0], acc[i][1], acc[i][2], acc[i][3]);
            float4 v1 = make_float4(acc[i][4], acc[i][5], acc[i][6], acc[i][7]);
            *(float4*)&C[(size_t)row * CH + tx * 8]     = v0;
            *(float4*)&C[(size_t)row * CH + tx * 8 + 4] = v1;
        }
    }
}

// ---------------- repack W1 (4,768,32) -> B (768,128) ----------------
__global__ void repack_w1(const float* __restrict__ W1, float* __restrict__ B)
{
    int idx = blockIdx.x * blockDim.x + threadIdx.x;
    if (idx >= IND * CH) return;
    int i = idx / CH, c = idx % CH;
    int h = c >> 5, o = c & 31;
    B[idx] = W1[(size_t)h * IND * 32 + (size_t)i * 32 + o];
}

// ---------------- s_src / s_dst: per node per head dot(z_row, a) ----------------
template<int HEADS>
__global__ __launch_bounds__(128) void compute_s(
    const float* __restrict__ z, const float* __restrict__ a,
    float* __restrict__ s_src, float* __restrict__ s_dst)
{
    const int n = blockIdx.x;
    const int c = threadIdx.x;
    const int D = CH / HEADS;
    const int head = c / D;
    const int d = c % D;
    const float v = z[(size_t)n * CH + c];
    float ps = v * a[head * 2 * D + d];
    float pd = v * a[head * 2 * D + D + d];
    __shared__ float ls[CH], ld_[CH];
    ls[c] = ps; ld_[c] = pd;
    __syncthreads();
    for (int off = D / 2; off > 0; off >>= 1) {
        if (d < off) { ls[c] += ls[c + off]; ld_[c] += ld_[c + off]; }
        __syncthreads();
    }
    if (d == 0) {
        s_src[n * HEADS + head] = ls[c];
        s_dst[n * HEADS + head] = ld_[c];
    }
}

// ---------------- order-preserving float<->uint ----------------
__device__ __forceinline__ unsigned enc_f(float f) {
    unsigned u = __float_as_uint(f);
    return (u & 0x80000000u) ? ~u : (u | 0x80000000u);
}
__device__ __forceinline__ float dec_f(unsigned k) {
    unsigned u = (k & 0x80000000u) ? (k & 0x7fffffffu) : ~k;
    return __uint_as_float(u);
}

template<int HEADS>
__global__ void edge_max(const int* __restrict__ src, const int* __restrict__ dst,
                         const float* __restrict__ s_src, const float* __restrict__ s_dst,
                         unsigned* __restrict__ maxb)
{
    int e = blockIdx.x * blockDim.x + threadIdx.x;
    if (e >= NE) return;
    int s = src[e], d = dst[e];
    #pragma unroll
    for (int h = 0; h < HEADS; ++h) {
        float v = s_src[s * HEADS + h] + s_dst[d * HEADS + h];
        v = v > 0.f ? v : 0.01f * v;
        atomicMax(&maxb[d * HEADS + h], enc_f(v));
    }
}

template<int HEADS>
__global__ void edge_expsum(const int* __restrict__ src, const int* __restrict__ dst,
                            const float* __restrict__ s_src, const float* __restrict__ s_dst,
                            const unsigned* __restrict__ maxb,
                            float* __restrict__ exb, float* __restrict__ denom)
{
    int e = blockIdx.x * blockDim.x + threadIdx.x;
    if (e >= NE) return;
    int s = src[e], d = dst[e];
    #pragma unroll
    for (int h = 0; h < HEADS; ++h) {
        float v = s_src[s * HEADS + h] + s_dst[d * HEADS + h];
        v = v > 0.f ? v : 0.01f * v;
        float m = dec_f(maxb[d * HEADS + h]);
        float ex = expf(v - m);
        exb[(size_t)e * HEADS + h] = ex;
        atomicAdd(&denom[d * HEADS + h], ex);
    }
}

// ---------------- CSR build ----------------
__global__ void count_k(const int* __restrict__ dst, int* __restrict__ counts)
{
    int e = blockIdx.x * blockDim.x + threadIdx.x;
    if (e < NE) atomicAdd(&counts[dst[e]], 1);
}

__global__ __launch_bounds__(1024) void exscan_k(const int* __restrict__ counts,
                                                 int* __restrict__ offsets)
{
    __shared__ int sums[1024];
    const int t = threadIdx.x;
    const int chunk = (NN + 1023) / 1024;
    const int beg = t * chunk;
    const int end = min(beg + chunk, NN);
    int s = 0;
    for (int j = beg; j < end; ++j) s += counts[j];
    sums[t] = s;
    __syncthreads();
    for (int off = 1; off < 1024; off <<= 1) {
        int v = (t >= off) ? sums[t - off] : 0;
        __syncthreads();
        sums[t] += v;
        __syncthreads();
    }
    int run = (t == 0) ? 0 : sums[t - 1];
    for (int j = beg; j < end; ++j) { offsets[j] = run; run += counts[j]; }
    if (t == 0) offsets[NN] = sums[1023];
}

__global__ void scatter_k(const int* __restrict__ dst, const int* __restrict__ offsets,
                          int* __restrict__ cursor, int* __restrict__ sorted_e)
{
    int e = blockIdx.x * blockDim.x + threadIdx.x;
    if (e >= NE) return;
    int d = dst[e];
    int p = offsets[d] + atomicAdd(&cursor[d], 1);
    sorted_e[p] = e;
}

// ---------------- aggregation: one block (128 thr) per dst node ----------------
template<int HEADS, bool ELU>
__global__ __launch_bounds__(128) void aggregate_k(
    const int* __restrict__ offsets, const int* __restrict__ sorted_e,
    const int* __restrict__ src, const float* __restrict__ z,
    const float* __restrict__ exb, const float* __restrict__ denom,
    float* __restrict__ out)
{
    const int n = blockIdx.x;
    const int c = threadIdx.x;
    const int D = CH / HEADS;
    const int head = c / D;
    const float inv = 1.0f / fmaxf(denom[n * HEADS + head], 1e-9f);
    const int beg = offsets[n], end = offsets[n + 1];
    float acc = 0.f;
    int i = beg;
    int e_cur = 0, s_cur = 0;
    if (i < end) { e_cur = sorted_e[i]; s_cur = src[e_cur]; }
    for (; i < end; ++i) {
        int e_nxt = 0, s_nxt = 0;
        if (i + 1 < end) { e_nxt = sorted_e[i + 1]; s_nxt = src[e_nxt]; }
        float alpha = exb[(size_t)e_cur * HEADS + head] * inv;
        acc = fmaf(alpha, z[(size_t)s_cur * CH + c], acc);
        e_cur = e_nxt; s_cur = s_nxt;
    }
    if (ELU) acc = acc > 0.f ? acc : expm1f(acc);
    out[(size_t)n * CH + c] = acc;
}

// ---------------- host ----------------
extern "C" void kernel_launch(void* const* d_in, const int* in_sizes, int n_in,
                              void* d_out, int out_size, void* d_ws, size_t ws_size,
                              hipStream_t stream)
{
    const float* h   = (const float*)d_in[0];
    const float* W1  = (const float*)d_in[1];
    const float* a1  = (const float*)d_in[2];
    const float* W2  = (const float*)d_in[3];
    const float* a2  = (const float*)d_in[4];
    const int*   src = (const int*)d_in[5];
    const int*   dst = (const int*)d_in[6];
    float* out = (float*)d_out;

    char* ws = (char*)d_ws;
    float*    Bbuf    = (float*)   (ws + 0);                 // 393216 B
    float*    z       = (float*)   (ws + 393216);            // 25.6 MB
    float*    h1      = (float*)   (ws + 25993216);          // 25.6 MB
    float*    s1s     = (float*)   (ws + 51593216);          // 800 KB
    float*    s1d     = (float*)   (ws + 52393216);          // 800 KB
    float*    s2s     = (float*)   (ws + 53193216);          // 200 KB
    float*    s2d     = (float*)   (ws + 53393216);          // 200 KB
    unsigned* maxb    = (unsigned*)(ws + 53593216);          // 800 KB
    float*    denom   = (float*)   (ws + 54393216);          // 800 KB
    float*    exb     = (float*)   (ws + 55193216);          // 12.8 MB
    int*      counts  = (int*)     (ws + 67993216);          // 200 KB
    int*      offsets = (int*)     (ws + 68193216);          // 200 KB (+4)
    int*      cursor  = (int*)     (ws + 68393280);          // 200 KB
    int*      sorted_e= (int*)     (ws + 68593280);          // 3.2 MB

    const int EB = 256;
    const int egrid = (NE + EB - 1) / EB;
    const int ggrid = (NN + BM - 1) / BM;

    // --- CSR build (shared by both layers) ---
    hipMemsetAsync(counts, 0, NN * sizeof(int), stream);
    hipMemsetAsync(cursor, 0, NN * sizeof(int), stream);
    count_k<<<egrid, EB, 0, stream>>>(dst, counts);
    exscan_k<<<1, 1024, 0, stream>>>(counts, offsets);
    scatter_k<<<egrid, EB, 0, stream>>>(dst, offsets, cursor, sorted_e);

    // --- layer 1 ---
    repack_w1<<<(IND * CH + 255) / 256, 256, 0, stream>>>(W1, Bbuf);
    gemm_f32<<<ggrid, 256, 0, stream>>>(h, Bbuf, z, NN, IND);
    compute_s<4><<<NN, 128, 0, stream>>>(z, a1, s1s, s1d);
    hipMemsetAsync(maxb, 0, NN * 4 * sizeof(unsigned), stream);
    hipMemsetAsync(denom, 0, NN * 4 * sizeof(float), stream);
    edge_max<4><<<egrid, EB, 0, stream>>>(src, dst, s1s, s1d, maxb);
    edge_expsum<4><<<egrid, EB, 0, stream>>>(src, dst, s1s, s1d, maxb, exb, denom);
    aggregate_k<4, true><<<NN, 128, 0, stream>>>(offsets, sorted_e, src, z, exb, denom, h1);

    // --- layer 2 ---
    gemm_f32<<<ggrid, 256, 0, stream>>>(h1, W2, z, NN, CH);
    compute_s<1><<<NN, 128, 0, stream>>>(z, a2, s2s, s2d);
    hipMemsetAsync(maxb, 0, NN * sizeof(unsigned), stream);
    hipMemsetAsync(denom, 0, NN * sizeof(float), stream);
    edge_max<1><<<egrid, EB, 0, stream>>>(src, dst, s2s, s2d, maxb);
    edge_expsum<1><<<egrid, EB, 0, stream>>>(src, dst, s2s, s2d, maxb, exb, denom);
    aggregate_k<1, false><<<NN, 128, 0, stream>>>(offsets, sorted_e, src, z, exb, denom, out);
}

// Round 2
// 972.612 us; speedup vs baseline: 1.1020x; 1.1020x over previous
//
#include <hip/hip_runtime.h>

#define NN 50000
#define NE 800000
#define IND 768
#define CH  128   // output channels per node for both layers

typedef __attribute__((ext_vector_type(8))) short bf16x8;
typedef __attribute__((ext_vector_type(4))) float f32x4;

// ---------------- bf16 split helpers ----------------
__device__ __forceinline__ unsigned short bf16_rne(float f) {
    unsigned u = __float_as_uint(f);
    u += 0x7fffu + ((u >> 16) & 1u);
    return (unsigned short)(u >> 16);
}
__device__ __forceinline__ float bf16_to_f(unsigned short b) {
    return __uint_as_float(((unsigned)b) << 16);
}

// ---------------- prep: W -> transposed bf16 hi/lo planes [N][K] ----------------
__global__ void prep_b1(const float* __restrict__ W1,
                        unsigned short* __restrict__ Bhi, unsigned short* __restrict__ Blo)
{
    int idx = blockIdx.x * blockDim.x + threadIdx.x;   // n*IND + k
    if (idx >= CH * IND) return;
    int n = idx / IND, k = idx % IND;
    float v = W1[(size_t)(n >> 5) * IND * 32 + (size_t)k * 32 + (n & 31)];
    unsigned short hi = bf16_rne(v);
    float lo = v - bf16_to_f(hi);
    Bhi[idx] = hi;
    Blo[idx] = bf16_rne(lo);
}

__global__ void prep_b2(const float* __restrict__ W2,
                        unsigned short* __restrict__ Bhi, unsigned short* __restrict__ Blo)
{
    int idx = blockIdx.x * blockDim.x + threadIdx.x;   // n*CH + k
    if (idx >= CH * CH) return;
    int n = idx / CH, k = idx % CH;
    float v = W2[(size_t)k * CH + n];
    unsigned short hi = bf16_rne(v);
    float lo = v - bf16_to_f(hi);
    Bhi[idx] = hi;
    Blo[idx] = bf16_rne(lo);
}

// ---------------- GEMM: C[M x 128] = A[M x K] * B[K x 128], split-bf16 MFMA ----------------
// A fp32 row-major; B given as transposed bf16 planes Bt[n][k] (hi, lo).
#define GBM 128
#define GBK 32
#define LDK 40   // padded LDS row stride in elements (80 B, 16B-aligned, conflict-spread)

__global__ __launch_bounds__(256, 2) void gemm_split(
    const float* __restrict__ A,
    const unsigned short* __restrict__ Bthi, const unsigned short* __restrict__ Btlo,
    float* __restrict__ C, int M, int K)
{
    __shared__ unsigned short Ahi[GBM][LDK];
    __shared__ unsigned short Alo[GBM][LDK];
    __shared__ unsigned short Bhi[CH][LDK];
    __shared__ unsigned short Blo[CH][LDK];

    const int t = threadIdx.x;
    const int lane = t & 63;
    const int w = t >> 6;          // wave 0..3
    const int wr = w >> 1;         // wave row (0..1) -> 64 rows
    const int wc = w & 1;          // wave col (0..1) -> 64 cols
    const int lrow = lane & 15;
    const int kg = lane >> 4;      // k-group 0..3 (8 k each)
    const int m0 = blockIdx.x * GBM;

    f32x4 acc[4][4];
    #pragma unroll
    for (int i = 0; i < 4; ++i)
        #pragma unroll
        for (int j = 0; j < 4; ++j) acc[i][j] = (f32x4)(0.f);

    for (int k0 = 0; k0 < K; k0 += GBK) {
        // ---- stage A: 128 rows x 32 k fp32 -> bf16 hi/lo. 512 chunks of 8k; 2/thread.
        #pragma unroll
        for (int i = 0; i < 2; ++i) {
            const int c = t + i * 256;
            const int row = c >> 2;
            const int j = c & 3;            // which 8-k chunk
            const int gr = m0 + row;
            float4 v0 = make_float4(0.f, 0.f, 0.f, 0.f);
            float4 v1 = make_float4(0.f, 0.f, 0.f, 0.f);
            if (gr < M) {
                const float* p = &A[(size_t)gr * K + k0 + j * 8];
                v0 = *(const float4*)p;
                v1 = *(const float4*)(p + 4);
            }
            float f[8] = {v0.x, v0.y, v0.z, v0.w, v1.x, v1.y, v1.z, v1.w};
            unsigned short hi[8], lo[8];
            #pragma unroll
            for (int q = 0; q < 8; ++q) {
                hi[q] = bf16_rne(f[q]);
                lo[q] = bf16_rne(f[q] - bf16_to_f(hi[q]));
            }
            *(uint4*)&Ahi[row][j * 8] = *(uint4*)hi;
            *(uint4*)&Alo[row][j * 8] = *(uint4*)lo;
        }
        // ---- stage B: two planes, each 128 n-rows x 32 k bf16. 1024 16B chunks; 4/thread.
        #pragma unroll
        for (int i = 0; i < 4; ++i) {
            const int c = t + i * 256;
            const int plane = c >> 9;
            const int cc = c & 511;
            const int row = cc >> 2;
            const int j = cc & 3;
            const unsigned short* srcp = (plane ? Btlo : Bthi) + (size_t)row * K + k0 + j * 8;
            uint4 v = *(const uint4*)srcp;
            if (plane) *(uint4*)&Blo[row][j * 8] = v;
            else       *(uint4*)&Bhi[row][j * 8] = v;
        }
        __syncthreads();

        // ---- fragments + MFMA
        bf16x8 ahi[4], alo[4];
        #pragma unroll
        for (int mi = 0; mi < 4; ++mi) {
            const int r = wr * 64 + mi * 16 + lrow;
            ahi[mi] = *(const bf16x8*)&Ahi[r][kg * 8];
            alo[mi] = *(const bf16x8*)&Alo[r][kg * 8];
        }
        #pragma unroll
        for (int ni = 0; ni < 4; ++ni) {
            const int rc = wc * 64 + ni * 16 + lrow;
            const bf16x8 bhi = *(const bf16x8*)&Bhi[rc][kg * 8];
            const bf16x8 blo = *(const bf16x8*)&Blo[rc][kg * 8];
            #pragma unroll
            for (int mi = 0; mi < 4; ++mi) {
                acc[mi][ni] = __builtin_amdgcn_mfma_f32_16x16x32_bf16(ahi[mi], bhi, acc[mi][ni], 0, 0, 0);
                acc[mi][ni] = __builtin_amdgcn_mfma_f32_16x16x32_bf16(ahi[mi], blo, acc[mi][ni], 0, 0, 0);
                acc[mi][ni] = __builtin_amdgcn_mfma_f32_16x16x32_bf16(alo[mi], bhi, acc[mi][ni], 0, 0, 0);
            }
        }
        __syncthreads();
    }

    // ---- C write: col = lane&15, row = (lane>>4)*4 + reg
    #pragma unroll
    for (int mi = 0; mi < 4; ++mi) {
        const int rbase = m0 + wr * 64 + mi * 16 + kg * 4;
        #pragma unroll
        for (int ni = 0; ni < 4; ++ni) {
            const int col = wc * 64 + ni * 16 + lrow;
            const f32x4 a = acc[mi][ni];
            #pragma unroll
            for (int j = 0; j < 4; ++j) {
                const int r = rbase + j;
                if (r < M) C[(size_t)r * CH + col] = a[j];
            }
        }
    }
}

// ---------------- s_src / s_dst: per node per head dot(z_row, a) ----------------
template<int HEADS>
__global__ __launch_bounds__(128) void compute_s(
    const float* __restrict__ z, const float* __restrict__ a,
    float* __restrict__ s_src, float* __restrict__ s_dst)
{
    const int n = blockIdx.x;
    const int c = threadIdx.x;
    const int D = CH / HEADS;
    const int head = c / D;
    const int d = c % D;
    const float v = z[(size_t)n * CH + c];
    float ps = v * a[head * 2 * D + d];
    float pd = v * a[head * 2 * D + D + d];
    __shared__ float ls[CH], ld_[CH];
    ls[c] = ps; ld_[c] = pd;
    __syncthreads();
    for (int off = D / 2; off > 0; off >>= 1) {
        if (d < off) { ls[c] += ls[c + off]; ld_[c] += ld_[c + off]; }
        __syncthreads();
    }
    if (d == 0) {
        s_src[n * HEADS + head] = ls[c];
        s_dst[n * HEADS + head] = ld_[c];
    }
}

// ---------------- order-preserving float<->uint ----------------
__device__ __forceinline__ unsigned enc_f(float f) {
    unsigned u = __float_as_uint(f);
    return (u & 0x80000000u) ? ~u : (u | 0x80000000u);
}
__device__ __forceinline__ float dec_f(unsigned k) {
    unsigned u = (k & 0x80000000u) ? (k & 0x7fffffffu) : ~k;
    return __uint_as_float(u);
}

template<int HEADS>
__global__ void edge_max(const int* __restrict__ src, const int* __restrict__ dst,
                         const float* __restrict__ s_src, const float* __restrict__ s_dst,
                         unsigned* __restrict__ maxb)
{
    int e = blockIdx.x * blockDim.x + threadIdx.x;
    if (e >= NE) return;
    int s = src[e], d = dst[e];
    #pragma unroll
    for (int h = 0; h < HEADS; ++h) {
        float v = s_src[s * HEADS + h] + s_dst[d * HEADS + h];
        v = v > 0.f ? v : 0.01f * v;
        atomicMax(&maxb[d * HEADS + h], enc_f(v));
    }
}

template<int HEADS>
__global__ void edge_expsum(const int* __restrict__ src, const int* __restrict__ dst,
                            const float* __restrict__ s_src, const float* __restrict__ s_dst,
                            const unsigned* __restrict__ maxb,
                            float* __restrict__ exb, float* __restrict__ denom)
{
    int e = blockIdx.x * blockDim.x + threadIdx.x;
    if (e >= NE) return;
    int s = src[e], d = dst[e];
    #pragma unroll
    for (int h = 0; h < HEADS; ++h) {
        float v = s_src[s * HEADS + h] + s_dst[d * HEADS + h];
        v = v > 0.f ? v : 0.01f * v;
        float m = dec_f(maxb[d * HEADS + h]);
        float ex = expf(v - m);
        exb[(size_t)e * HEADS + h] = ex;
        atomicAdd(&denom[d * HEADS + h], ex);
    }
}

// ---------------- CSR build ----------------
__global__ void count_k(const int* __restrict__ dst, int* __restrict__ counts)
{
    int e = blockIdx.x * blockDim.x + threadIdx.x;
    if (e < NE) atomicAdd(&counts[dst[e]], 1);
}

__global__ __launch_bounds__(1024) void exscan_k(const int* __restrict__ counts,
                                                 int* __restrict__ offsets)
{
    __shared__ int sums[1024];
    const int t = threadIdx.x;
    const int chunk = (NN + 1023) / 1024;
    const int beg = t * chunk;
    const int end = min(beg + chunk, NN);
    int s = 0;
    for (int j = beg; j < end; ++j) s += counts[j];
    sums[t] = s;
    __syncthreads();
    for (int off = 1; off < 1024; off <<= 1) {
        int v = (t >= off) ? sums[t - off] : 0;
        __syncthreads();
        sums[t] += v;
        __syncthreads();
    }
    int run = (t == 0) ? 0 : sums[t - 1];
    for (int j = beg; j < end; ++j) { offsets[j] = run; run += counts[j]; }
    if (t == 0) offsets[NN] = sums[1023];
}

__global__ void scatter_k(const int* __restrict__ dst, const int* __restrict__ offsets,
                          int* __restrict__ cursor, int* __restrict__ sorted_e)
{
    int e = blockIdx.x * blockDim.x + threadIdx.x;
    if (e >= NE) return;
    int d = dst[e];
    int p = offsets[d] + atomicAdd(&cursor[d], 1);
    sorted_e[p] = e;
}

// ---------------- aggregation: one block (128 thr) per dst node ----------------
template<int HEADS, bool ELU>
__global__ __launch_bounds__(128) void aggregate_k(
    const int* __restrict__ offsets, const int* __restrict__ sorted_e,
    const int* __restrict__ src, const float* __restrict__ z,
    const float* __restrict__ exb, const float* __restrict__ denom,
    float* __restrict__ out)
{
    const int n = blockIdx.x;
    const int c = threadIdx.x;
    const int D = CH / HEADS;
    const int head = c / D;
    const float inv = 1.0f / fmaxf(denom[n * HEADS + head], 1e-9f);
    const int beg = offsets[n], end = offsets[n + 1];
    float acc = 0.f;
    int i = beg;
    int e_cur = 0, s_cur = 0;
    if (i < end) { e_cur = sorted_e[i]; s_cur = src[e_cur]; }
    for (; i < end; ++i) {
        int e_nxt = 0, s_nxt = 0;
        if (i + 1 < end) { e_nxt = sorted_e[i + 1]; s_nxt = src[e_nxt]; }
        float alpha = exb[(size_t)e_cur * HEADS + head] * inv;
        acc = fmaf(alpha, z[(size_t)s_cur * CH + c], acc);
        e_cur = e_nxt; s_cur = s_nxt;
    }
    if (ELU) acc = acc > 0.f ? acc : expm1f(acc);
    out[(size_t)n * CH + c] = acc;
}

// ---------------- host ----------------
extern "C" void kernel_launch(void* const* d_in, const int* in_sizes, int n_in,
                              void* d_out, int out_size, void* d_ws, size_t ws_size,
                              hipStream_t stream)
{
    const float* h   = (const float*)d_in[0];
    const float* W1  = (const float*)d_in[1];
    const float* a1  = (const float*)d_in[2];
    const float* W2  = (const float*)d_in[3];
    const float* a2  = (const float*)d_in[4];
    const int*   src = (const int*)d_in[5];
    const int*   dst = (const int*)d_in[6];
    float* out = (float*)d_out;

    char* ws = (char*)d_ws;
    unsigned short* Bthi1 = (unsigned short*)(ws + 0);        // 196608 B
    unsigned short* Btlo1 = (unsigned short*)(ws + 196608);   // 196608 B
    float*    z       = (float*)   (ws + 393216);             // 25.6 MB
    float*    h1      = (float*)   (ws + 25993216);           // 25.6 MB
    float*    s1s     = (float*)   (ws + 51593216);           // 800 KB
    float*    s1d     = (float*)   (ws + 52393216);           // 800 KB
    float*    s2s     = (float*)   (ws + 53193216);           // 200 KB
    float*    s2d     = (float*)   (ws + 53393216);           // 200 KB
    unsigned* maxb    = (unsigned*)(ws + 53593216);           // 800 KB
    float*    denom   = (float*)   (ws + 54393216);           // 800 KB
    float*    exb     = (float*)   (ws + 55193216);           // 12.8 MB
    int*      counts  = (int*)     (ws + 67993216);           // 200 KB
    int*      offsets = (int*)     (ws + 68193216);           // 200 KB (+4)
    int*      cursor  = (int*)     (ws + 68393280);           // 200 KB
    int*      sorted_e= (int*)     (ws + 68593280);           // 3.2 MB
    unsigned short* Bthi2 = (unsigned short*)(ws + 71793280); // 32768 B
    unsigned short* Btlo2 = (unsigned short*)(ws + 71826048); // 32768 B

    const int EB = 256;
    const int egrid = (NE + EB - 1) / EB;
    const int ggrid = (NN + GBM - 1) / GBM;

    // --- CSR build (shared by both layers) ---
    hipMemsetAsync(counts, 0, NN * sizeof(int), stream);
    hipMemsetAsync(cursor, 0, NN * sizeof(int), stream);
    count_k<<<egrid, EB, 0, stream>>>(dst, counts);
    exscan_k<<<1, 1024, 0, stream>>>(counts, offsets);
    scatter_k<<<egrid, EB, 0, stream>>>(dst, offsets, cursor, sorted_e);

    // --- weight prep (split bf16, transposed) ---
    prep_b1<<<(CH * IND + 255) / 256, 256, 0, stream>>>(W1, Bthi1, Btlo1);
    prep_b2<<<(CH * CH + 255) / 256, 256, 0, stream>>>(W2, Bthi2, Btlo2);

    // --- layer 1 ---
    gemm_split<<<ggrid, 256, 0, stream>>>(h, Bthi1, Btlo1, z, NN, IND);
    compute_s<4><<<NN, 128, 0, stream>>>(z, a1, s1s, s1d);
    hipMemsetAsync(maxb, 0, NN * 4 * sizeof(unsigned), stream);
    hipMemsetAsync(denom, 0, NN * 4 * sizeof(float), stream);
    edge_max<4><<<egrid, EB, 0, stream>>>(src, dst, s1s, s1d, maxb);
    edge_expsum<4><<<egrid, EB, 0, stream>>>(src, dst, s1s, s1d, maxb, exb, denom);
    aggregate_k<4, true><<<NN, 128, 0, stream>>>(offsets, sorted_e, src, z, exb, denom, h1);

    // --- layer 2 ---
    gemm_split<<<ggrid, 256, 0, stream>>>(h1, Bthi2, Btlo2, z, NN, CH);
    compute_s<1><<<NN, 128, 0, stream>>>(z, a2, s2s, s2d);
    hipMemsetAsync(maxb, 0, NN * sizeof(unsigned), stream);
    hipMemsetAsync(denom, 0, NN * sizeof(float), stream);
    edge_max<1><<<egrid, EB, 0, stream>>>(src, dst, s2s, s2d, maxb);
    edge_expsum<1><<<egrid, EB, 0, stream>>>(src, dst, s2s, s2d, maxb, exb, denom);
    aggregate_k<1, false><<<NN, 128, 0, stream>>>(offsets, sorted_e, src, z, exb, denom, out);
}

// Round 3
// 452.894 us; speedup vs baseline: 2.3667x; 2.1475x over previous
//
#include <hip/hip_runtime.h>

#define NN 50000
#define NE 800000
#define IND 768
#define CH  128   // output channels per node for both layers

typedef __attribute__((ext_vector_type(8))) short bf16x8;
typedef __attribute__((ext_vector_type(4))) float f32x4;

// ---------------- bf16 split helpers ----------------
__device__ __forceinline__ unsigned short bf16_rne(float f) {
    unsigned u = __float_as_uint(f);
    u += 0x7fffu + ((u >> 16) & 1u);
    return (unsigned short)(u >> 16);
}
__device__ __forceinline__ float bf16_to_f(unsigned short b) {
    return __uint_as_float(((unsigned)b) << 16);
}

// ---------------- prep: W -> transposed bf16 hi/lo planes [N][K] ----------------
__global__ void prep_b1(const float* __restrict__ W1,
                        unsigned short* __restrict__ Bhi, unsigned short* __restrict__ Blo)
{
    int idx = blockIdx.x * blockDim.x + threadIdx.x;   // n*IND + k
    if (idx >= CH * IND) return;
    int n = idx / IND, k = idx % IND;
    float v = W1[(size_t)(n >> 5) * IND * 32 + (size_t)k * 32 + (n & 31)];
    unsigned short hi = bf16_rne(v);
    float lo = v - bf16_to_f(hi);
    Bhi[idx] = hi;
    Blo[idx] = bf16_rne(lo);
}

__global__ void prep_b2(const float* __restrict__ W2,
                        unsigned short* __restrict__ Bhi, unsigned short* __restrict__ Blo)
{
    int idx = blockIdx.x * blockDim.x + threadIdx.x;   // n*CH + k
    if (idx >= CH * CH) return;
    int n = idx / CH, k = idx % CH;
    float v = W2[(size_t)k * CH + n];
    unsigned short hi = bf16_rne(v);
    float lo = v - bf16_to_f(hi);
    Bhi[idx] = hi;
    Blo[idx] = bf16_rne(lo);
}

// ---------------- GEMM: C[M x 128] = A[M x K] * B[K x 128], split-bf16 MFMA ----------------
#define GBM 128
#define GBK 32
#define LDK 40   // padded LDS row stride (80 B, 16B-aligned)

__global__ __launch_bounds__(256, 2) void gemm_split(
    const float* __restrict__ A,
    const unsigned short* __restrict__ Bthi, const unsigned short* __restrict__ Btlo,
    float* __restrict__ C, int M, int K)
{
    __shared__ unsigned short Ahi[GBM][LDK];
    __shared__ unsigned short Alo[GBM][LDK];
    __shared__ unsigned short Bhi[CH][LDK];
    __shared__ unsigned short Blo[CH][LDK];

    const int t = threadIdx.x;
    const int lane = t & 63;
    const int w = t >> 6;
    const int wr = w >> 1;
    const int wc = w & 1;
    const int lrow = lane & 15;
    const int kg = lane >> 4;
    const int m0 = blockIdx.x * GBM;

    f32x4 acc[4][4];
    #pragma unroll
    for (int i = 0; i < 4; ++i)
        #pragma unroll
        for (int j = 0; j < 4; ++j) acc[i][j] = (f32x4)(0.f);

    for (int k0 = 0; k0 < K; k0 += GBK) {
        #pragma unroll
        for (int i = 0; i < 2; ++i) {
            const int c = t + i * 256;
            const int row = c >> 2;
            const int j = c & 3;
            const int gr = m0 + row;
            float4 v0 = make_float4(0.f, 0.f, 0.f, 0.f);
            float4 v1 = make_float4(0.f, 0.f, 0.f, 0.f);
            if (gr < M) {
                const float* p = &A[(size_t)gr * K + k0 + j * 8];
                v0 = *(const float4*)p;
                v1 = *(const float4*)(p + 4);
            }
            float f[8] = {v0.x, v0.y, v0.z, v0.w, v1.x, v1.y, v1.z, v1.w};
            unsigned short hi[8], lo[8];
            #pragma unroll
            for (int q = 0; q < 8; ++q) {
                hi[q] = bf16_rne(f[q]);
                lo[q] = bf16_rne(f[q] - bf16_to_f(hi[q]));
            }
            *(uint4*)&Ahi[row][j * 8] = *(uint4*)hi;
            *(uint4*)&Alo[row][j * 8] = *(uint4*)lo;
        }
        #pragma unroll
        for (int i = 0; i < 4; ++i) {
            const int c = t + i * 256;
            const int plane = c >> 9;
            const int cc = c & 511;
            const int row = cc >> 2;
            const int j = cc & 3;
            const unsigned short* srcp = (plane ? Btlo : Bthi) + (size_t)row * K + k0 + j * 8;
            uint4 v = *(const uint4*)srcp;
            if (plane) *(uint4*)&Blo[row][j * 8] = v;
            else       *(uint4*)&Bhi[row][j * 8] = v;
        }
        __syncthreads();

        bf16x8 ahi[4], alo[4];
        #pragma unroll
        for (int mi = 0; mi < 4; ++mi) {
            const int r = wr * 64 + mi * 16 + lrow;
            ahi[mi] = *(const bf16x8*)&Ahi[r][kg * 8];
            alo[mi] = *(const bf16x8*)&Alo[r][kg * 8];
        }
        #pragma unroll
        for (int ni = 0; ni < 4; ++ni) {
            const int rc = wc * 64 + ni * 16 + lrow;
            const bf16x8 bhi = *(const bf16x8*)&Bhi[rc][kg * 8];
            const bf16x8 blo = *(const bf16x8*)&Blo[rc][kg * 8];
            #pragma unroll
            for (int mi = 0; mi < 4; ++mi) {
                acc[mi][ni] = __builtin_amdgcn_mfma_f32_16x16x32_bf16(ahi[mi], bhi, acc[mi][ni], 0, 0, 0);
                acc[mi][ni] = __builtin_amdgcn_mfma_f32_16x16x32_bf16(ahi[mi], blo, acc[mi][ni], 0, 0, 0);
                acc[mi][ni] = __builtin_amdgcn_mfma_f32_16x16x32_bf16(alo[mi], bhi, acc[mi][ni], 0, 0, 0);
            }
        }
        __syncthreads();
    }

    #pragma unroll
    for (int mi = 0; mi < 4; ++mi) {
        const int rbase = m0 + wr * 64 + mi * 16 + kg * 4;
        #pragma unroll
        for (int ni = 0; ni < 4; ++ni) {
            const int col = wc * 64 + ni * 16 + lrow;
            const f32x4 a = acc[mi][ni];
            #pragma unroll
            for (int j = 0; j < 4; ++j) {
                const int r = rbase + j;
                if (r < M) C[(size_t)r * CH + col] = a[j];
            }
        }
    }
}

// ---------------- s_src / s_dst: one wave per node, shuffle reduce ----------------
template<int HEADS>
__global__ __launch_bounds__(256) void compute_s_w(
    const float* __restrict__ z, const float* __restrict__ a,
    float* __restrict__ s_src, float* __restrict__ s_dst)
{
    const int wid = threadIdx.x >> 6;
    const int lane = threadIdx.x & 63;
    const int n = blockIdx.x * 4 + wid;
    if (n >= NN) return;
    const int D = CH / HEADS;
    const float2 v = *(const float2*)&z[(size_t)n * CH + lane * 2];
    const int c0 = lane * 2;
    const int head = c0 / D;
    const int d0 = c0 % D;
    float ps = v.x * a[head * 2 * D + d0]     + v.y * a[head * 2 * D + d0 + 1];
    float pd = v.x * a[head * 2 * D + D + d0] + v.y * a[head * 2 * D + D + d0 + 1];
    #pragma unroll
    for (int off = 1; off < D / 2; off <<= 1) {
        ps += __shfl_xor(ps, off, 64);
        pd += __shfl_xor(pd, off, 64);
    }
    if ((lane % (D / 2)) == 0) {
        s_src[n * HEADS + head] = ps;
        s_dst[n * HEADS + head] = pd;
    }
}

// ---------------- CSR build ----------------
__global__ void count_k(const int* __restrict__ dst, int* __restrict__ counts)
{
    int e = blockIdx.x * blockDim.x + threadIdx.x;
    if (e < NE) atomicAdd(&counts[dst[e]], 1);
}

__global__ __launch_bounds__(1024) void exscan_k(const int* __restrict__ counts,
                                                 int* __restrict__ offsets)
{
    __shared__ int sums[1024];
    const int t = threadIdx.x;
    const int chunk = (NN + 1023) / 1024;
    const int beg = t * chunk;
    const int end = min(beg + chunk, NN);
    int s = 0;
    for (int j = beg; j < end; ++j) s += counts[j];
    sums[t] = s;
    __syncthreads();
    for (int off = 1; off < 1024; off <<= 1) {
        int v = (t >= off) ? sums[t - off] : 0;
        __syncthreads();
        sums[t] += v;
        __syncthreads();
    }
    int run = (t == 0) ? 0 : sums[t - 1];
    for (int j = beg; j < end; ++j) { offsets[j] = run; run += counts[j]; }
    if (t == 0) offsets[NN] = sums[1023];
}

__global__ void scatter_k(const int* __restrict__ dst, const int* __restrict__ offsets,
                          int* __restrict__ cursor, int* __restrict__ sorted_e)
{
    int e = blockIdx.x * blockDim.x + threadIdx.x;
    if (e >= NE) return;
    int d = dst[e];
    int p = offsets[d] + atomicAdd(&cursor[d], 1);
    sorted_e[p] = e;
}

// ---------------- fused softmax + aggregation: one block (128 thr) per dst node ----------------
template<int HEADS, bool ELU>
__global__ __launch_bounds__(128) void fused_agg(
    const int* __restrict__ offsets, const int* __restrict__ sorted_e,
    const int* __restrict__ src,
    const float* __restrict__ s_src, const float* __restrict__ s_dst,
    const float* __restrict__ z, float* __restrict__ out)
{
    const int n = blockIdx.x;
    const int t = threadIdx.x;
    const int beg = offsets[n], end = offsets[n + 1];
    const int head_c = (HEADS == 4) ? (t >> 5) : 0;   // this thread's output-channel head

    if (end == beg) {                                  // no incoming edges -> 0
        out[(size_t)n * CH + t] = 0.f;
        return;
    }

    __shared__ float red[128];
    __shared__ float m_sh[HEADS], inv_sh[HEADS], sdst_sh[HEADS];
    __shared__ int   esrc[32];
    __shared__ float exl[32][HEADS];

    if (t < HEADS) sdst_sh[t] = s_dst[n * HEADS + t];
    __syncthreads();

    const int NS = 128 / HEADS;        // slots
    const int slot = t / HEADS;
    const int head = t % HEADS;
    const float sd = sdst_sh[head];

    // ---- pass 1: per-head max ----
    float pm = -INFINITY;
    for (int i = beg + slot; i < end; i += NS) {
        int s = src[sorted_e[i]];
        float v = s_src[s * HEADS + head] + sd;
        v = v > 0.f ? v : 0.01f * v;
        pm = fmaxf(pm, v);
    }
    red[t] = pm;
    __syncthreads();
    #pragma unroll
    for (int off = NS / 2; off > 0; off >>= 1) {
        if (slot < off) red[t] = fmaxf(red[t], red[t + off * HEADS]);
        __syncthreads();
    }
    if (t < HEADS) m_sh[t] = red[t];
    __syncthreads();
    const float m = m_sh[head];

    // ---- pass 2: per-head sum of exp ----
    float ps = 0.f;
    for (int i = beg + slot; i < end; i += NS) {
        int s = src[sorted_e[i]];
        float v = s_src[s * HEADS + head] + sd;
        v = v > 0.f ? v : 0.01f * v;
        ps += __expf(v - m);
    }
    red[t] = ps;
    __syncthreads();
    #pragma unroll
    for (int off = NS / 2; off > 0; off >>= 1) {
        if (slot < off) red[t] += red[t + off * HEADS];
        __syncthreads();
    }
    if (t < HEADS) inv_sh[t] = 1.0f / fmaxf(red[t], 1e-9f);
    __syncthreads();

    // ---- pass 3: chunked accumulate ----
    float acc = 0.f;
    for (int c0 = beg; c0 < end; c0 += 32) {
        const int nchunk = min(32, end - c0);
        if (t < 32 && t < nchunk) esrc[t] = src[sorted_e[c0 + t]];
        __syncthreads();
        if (HEADS == 4) {
            const int j = t >> 2, hh = t & 3;
            if (j < nchunk) {
                float v = s_src[esrc[j] * 4 + hh] + sdst_sh[hh];
                v = v > 0.f ? v : 0.01f * v;
                exl[j][hh] = __expf(v - m_sh[hh]) * inv_sh[hh];
            }
        } else {
            if (t < nchunk) {
                float v = s_src[esrc[t]] + sdst_sh[0];
                v = v > 0.f ? v : 0.01f * v;
                exl[t][0] = __expf(v - m_sh[0]) * inv_sh[0];
            }
        }
        __syncthreads();
        for (int j = 0; j < nchunk; ++j)
            acc = fmaf(exl[j][head_c], z[(size_t)esrc[j] * CH + t], acc);
        __syncthreads();
    }

    if (ELU) acc = acc > 0.f ? acc : expm1f(acc);
    out[(size_t)n * CH + t] = acc;
}

// ---------------- host ----------------
extern "C" void kernel_launch(void* const* d_in, const int* in_sizes, int n_in,
                              void* d_out, int out_size, void* d_ws, size_t ws_size,
                              hipStream_t stream)
{
    const float* h   = (const float*)d_in[0];
    const float* W1  = (const float*)d_in[1];
    const float* a1  = (const float*)d_in[2];
    const float* W2  = (const float*)d_in[3];
    const float* a2  = (const float*)d_in[4];
    const int*   src = (const int*)d_in[5];
    const int*   dst = (const int*)d_in[6];
    float* out = (float*)d_out;

    char* ws = (char*)d_ws;
    unsigned short* Bthi1 = (unsigned short*)(ws + 0);        // 196608 B
    unsigned short* Btlo1 = (unsigned short*)(ws + 196608);   // 196608 B
    float*    z       = (float*)   (ws + 393216);             // 25.6 MB
    float*    h1      = (float*)   (ws + 25993216);           // 25.6 MB
    float*    s1s     = (float*)   (ws + 51593216);           // 800 KB
    float*    s1d     = (float*)   (ws + 52393216);           // 800 KB
    float*    s2s     = (float*)   (ws + 53193216);           // 200 KB
    float*    s2d     = (float*)   (ws + 53393216);           // 200 KB
    int*      counts  = (int*)     (ws + 67993216);           // 200 KB
    int*      offsets = (int*)     (ws + 68193216);           // 200 KB (+4)
    int*      cursor  = (int*)     (ws + 68393280);           // 200 KB
    int*      sorted_e= (int*)     (ws + 68593280);           // 3.2 MB
    unsigned short* Bthi2 = (unsigned short*)(ws + 71793280); // 32768 B
    unsigned short* Btlo2 = (unsigned short*)(ws + 71826048); // 32768 B

    const int EB = 256;
    const int egrid = (NE + EB - 1) / EB;
    const int ggrid = (NN + GBM - 1) / GBM;
    const int sgrid = (NN + 3) / 4;

    // --- CSR build (shared by both layers) ---
    hipMemsetAsync(counts, 0, NN * sizeof(int), stream);
    hipMemsetAsync(cursor, 0, NN * sizeof(int), stream);
    count_k<<<egrid, EB, 0, stream>>>(dst, counts);
    exscan_k<<<1, 1024, 0, stream>>>(counts, offsets);
    scatter_k<<<egrid, EB, 0, stream>>>(dst, offsets, cursor, sorted_e);

    // --- weight prep (split bf16, transposed) ---
    prep_b1<<<(CH * IND + 255) / 256, 256, 0, stream>>>(W1, Bthi1, Btlo1);
    prep_b2<<<(CH * CH + 255) / 256, 256, 0, stream>>>(W2, Bthi2, Btlo2);

    // --- layer 1 ---
    gemm_split<<<ggrid, 256, 0, stream>>>(h, Bthi1, Btlo1, z, NN, IND);
    compute_s_w<4><<<sgrid, 256, 0, stream>>>(z, a1, s1s, s1d);
    fused_agg<4, true><<<NN, 128, 0, stream>>>(offsets, sorted_e, src, s1s, s1d, z, h1);

    // --- layer 2 ---
    gemm_split<<<ggrid, 256, 0, stream>>>(h1, Bthi2, Btlo2, z, NN, CH);
    compute_s_w<1><<<sgrid, 256, 0, stream>>>(z, a2, s2s, s2d);
    fused_agg<1, false><<<NN, 128, 0, stream>>>(offsets, sorted_e, src, s2s, s2d, z, out);
}

// Round 4
// 332.147 us; speedup vs baseline: 3.2270x; 1.3635x over previous
//
#include <hip/hip_runtime.h>

#define NN 50000
#define NE 800000
#define IND 768
#define CH  128   // output channels per node for both layers
#define NBLK 196  // ceil(NN/256)

typedef __attribute__((ext_vector_type(8))) short bf16x8;
typedef __attribute__((ext_vector_type(4))) float f32x4;

// ---------------- bf16 split helpers ----------------
__device__ __forceinline__ unsigned short bf16_rne(float f) {
    unsigned u = __float_as_uint(f);
    u += 0x7fffu + ((u >> 16) & 1u);
    return (unsigned short)(u >> 16);
}
__device__ __forceinline__ float bf16_to_f(unsigned short b) {
    return __uint_as_float(((unsigned)b) << 16);
}

// ---------------- prep: W -> transposed bf16 hi/lo planes [N][K] ----------------
__global__ void prep_b1(const float* __restrict__ W1,
                        unsigned short* __restrict__ Bhi, unsigned short* __restrict__ Blo)
{
    int idx = blockIdx.x * blockDim.x + threadIdx.x;   // n*IND + k
    if (idx >= CH * IND) return;
    int n = idx / IND, k = idx % IND;
    float v = W1[(size_t)(n >> 5) * IND * 32 + (size_t)k * 32 + (n & 31)];
    unsigned short hi = bf16_rne(v);
    float lo = v - bf16_to_f(hi);
    Bhi[idx] = hi;
    Blo[idx] = bf16_rne(lo);
}

__global__ void prep_b2(const float* __restrict__ W2,
                        unsigned short* __restrict__ Bhi, unsigned short* __restrict__ Blo)
{
    int idx = blockIdx.x * blockDim.x + threadIdx.x;   // n*CH + k
    if (idx >= CH * CH) return;
    int n = idx / CH, k = idx % CH;
    float v = W2[(size_t)k * CH + n];
    unsigned short hi = bf16_rne(v);
    float lo = v - bf16_to_f(hi);
    Bhi[idx] = hi;
    Blo[idx] = bf16_rne(lo);
}

// ---------------- GEMM: C[M x 128] = A[M x K] * B[K x 128], split-bf16 MFMA ----------------
#define GBM 128
#define GBK 32
#define LDK 40   // padded LDS row stride (80 B, 16B-aligned)

__global__ __launch_bounds__(256, 2) void gemm_split(
    const float* __restrict__ A,
    const unsigned short* __restrict__ Bthi, const unsigned short* __restrict__ Btlo,
    float* __restrict__ C, int M, int K)
{
    __shared__ unsigned short Ahi[GBM][LDK];
    __shared__ unsigned short Alo[GBM][LDK];
    __shared__ unsigned short Bhi[CH][LDK];
    __shared__ unsigned short Blo[CH][LDK];

    const int t = threadIdx.x;
    const int lane = t & 63;
    const int w = t >> 6;
    const int wr = w >> 1;
    const int wc = w & 1;
    const int lrow = lane & 15;
    const int kg = lane >> 4;
    const int m0 = blockIdx.x * GBM;

    f32x4 acc[4][4];
    #pragma unroll
    for (int i = 0; i < 4; ++i)
        #pragma unroll
        for (int j = 0; j < 4; ++j) acc[i][j] = (f32x4)(0.f);

    for (int k0 = 0; k0 < K; k0 += GBK) {
        #pragma unroll
        for (int i = 0; i < 2; ++i) {
            const int c = t + i * 256;
            const int row = c >> 2;
            const int j = c & 3;
            const int gr = m0 + row;
            float4 v0 = make_float4(0.f, 0.f, 0.f, 0.f);
            float4 v1 = make_float4(0.f, 0.f, 0.f, 0.f);
            if (gr < M) {
                const float* p = &A[(size_t)gr * K + k0 + j * 8];
                v0 = *(const float4*)p;
                v1 = *(const float4*)(p + 4);
            }
            float f[8] = {v0.x, v0.y, v0.z, v0.w, v1.x, v1.y, v1.z, v1.w};
            unsigned short hi[8], lo[8];
            #pragma unroll
            for (int q = 0; q < 8; ++q) {
                hi[q] = bf16_rne(f[q]);
                lo[q] = bf16_rne(f[q] - bf16_to_f(hi[q]));
            }
            *(uint4*)&Ahi[row][j * 8] = *(uint4*)hi;
            *(uint4*)&Alo[row][j * 8] = *(uint4*)lo;
        }
        #pragma unroll
        for (int i = 0; i < 4; ++i) {
            const int c = t + i * 256;
            const int plane = c >> 9;
            const int cc = c & 511;
            const int row = cc >> 2;
            const int j = cc & 3;
            const unsigned short* srcp = (plane ? Btlo : Bthi) + (size_t)row * K + k0 + j * 8;
            uint4 v = *(const uint4*)srcp;
            if (plane) *(uint4*)&Blo[row][j * 8] = v;
            else       *(uint4*)&Bhi[row][j * 8] = v;
        }
        __syncthreads();

        bf16x8 ahi[4], alo[4];
        #pragma unroll
        for (int mi = 0; mi < 4; ++mi) {
            const int r = wr * 64 + mi * 16 + lrow;
            ahi[mi] = *(const bf16x8*)&Ahi[r][kg * 8];
            alo[mi] = *(const bf16x8*)&Alo[r][kg * 8];
        }
        #pragma unroll
        for (int ni = 0; ni < 4; ++ni) {
            const int rc = wc * 64 + ni * 16 + lrow;
            const bf16x8 bhi = *(const bf16x8*)&Bhi[rc][kg * 8];
            const bf16x8 blo = *(const bf16x8*)&Blo[rc][kg * 8];
            #pragma unroll
            for (int mi = 0; mi < 4; ++mi) {
                acc[mi][ni] = __builtin_amdgcn_mfma_f32_16x16x32_bf16(ahi[mi], bhi, acc[mi][ni], 0, 0, 0);
                acc[mi][ni] = __builtin_amdgcn_mfma_f32_16x16x32_bf16(ahi[mi], blo, acc[mi][ni], 0, 0, 0);
                acc[mi][ni] = __builtin_amdgcn_mfma_f32_16x16x32_bf16(alo[mi], bhi, acc[mi][ni], 0, 0, 0);
            }
        }
        __syncthreads();
    }

    #pragma unroll
    for (int mi = 0; mi < 4; ++mi) {
        const int rbase = m0 + wr * 64 + mi * 16 + kg * 4;
        #pragma unroll
        for (int ni = 0; ni < 4; ++ni) {
            const int col = wc * 64 + ni * 16 + lrow;
            const f32x4 a = acc[mi][ni];
            #pragma unroll
            for (int j = 0; j < 4; ++j) {
                const int r = rbase + j;
                if (r < M) C[(size_t)r * CH + col] = a[j];
            }
        }
    }
}

// ---------------- s_src / s_dst: one wave per node, shuffle reduce ----------------
template<int HEADS>
__global__ __launch_bounds__(256) void compute_s_w(
    const float* __restrict__ z, const float* __restrict__ a,
    float* __restrict__ s_src, float* __restrict__ s_dst)
{
    const int wid = threadIdx.x >> 6;
    const int lane = threadIdx.x & 63;
    const int n = blockIdx.x * 4 + wid;
    if (n >= NN) return;
    const int D = CH / HEADS;
    const float2 v = *(const float2*)&z[(size_t)n * CH + lane * 2];
    const int c0 = lane * 2;
    const int head = c0 / D;
    const int d0 = c0 % D;
    float ps = v.x * a[head * 2 * D + d0]     + v.y * a[head * 2 * D + d0 + 1];
    float pd = v.x * a[head * 2 * D + D + d0] + v.y * a[head * 2 * D + D + d0 + 1];
    #pragma unroll
    for (int off = 1; off < D / 2; off <<= 1) {
        ps += __shfl_xor(ps, off, 64);
        pd += __shfl_xor(pd, off, 64);
    }
    if ((lane % (D / 2)) == 0) {
        s_src[n * HEADS + head] = ps;
        s_dst[n * HEADS + head] = pd;
    }
}

// ---------------- CSR build ----------------
__global__ void count_k(const int* __restrict__ dst, int* __restrict__ counts)
{
    int e = blockIdx.x * blockDim.x + threadIdx.x;
    if (e < NE) atomicAdd(&counts[dst[e]], 1);
}

// 3-phase exclusive scan over counts[NN] -> offsets[NN+1]
__global__ __launch_bounds__(256) void scan1(const int* __restrict__ counts,
                                             int* __restrict__ exc, int* __restrict__ bsum)
{
    __shared__ int s[256];
    const int t = threadIdx.x;
    const int i = blockIdx.x * 256 + t;
    const int val = (i < NN) ? counts[i] : 0;
    s[t] = val;
    __syncthreads();
    #pragma unroll
    for (int off = 1; off < 256; off <<= 1) {
        int v = (t >= off) ? s[t - off] : 0;
        __syncthreads();
        s[t] += v;
        __syncthreads();
    }
    if (i < NN) exc[i] = s[t] - val;
    if (t == 255) bsum[blockIdx.x] = s[255];
}

__global__ __launch_bounds__(256) void scan2(const int* __restrict__ bsum,
                                             int* __restrict__ bexc)
{
    __shared__ int s[256];
    const int t = threadIdx.x;
    const int val = (t < NBLK) ? bsum[t] : 0;
    s[t] = val;
    __syncthreads();
    #pragma unroll
    for (int off = 1; off < 256; off <<= 1) {
        int v = (t >= off) ? s[t - off] : 0;
        __syncthreads();
        s[t] += v;
        __syncthreads();
    }
    bexc[t] = s[t] - val;
}

__global__ __launch_bounds__(256) void scan3(const int* __restrict__ exc,
                                             const int* __restrict__ bexc,
                                             int* __restrict__ offsets)
{
    const int i = blockIdx.x * 256 + threadIdx.x;
    if (i < NN) offsets[i] = exc[i] + bexc[i >> 8];
    if (i == 0) offsets[NN] = NE;
}

// scatter permuted SOURCE ids directly: es[p] = src[e]  (CSR payload, 1-level gather later)
__global__ void scatter_es(const int* __restrict__ src, const int* __restrict__ dst,
                           const int* __restrict__ offsets, int* __restrict__ cursor,
                           int* __restrict__ es)
{
    int e = blockIdx.x * blockDim.x + threadIdx.x;
    if (e >= NE) return;
    int d = dst[e];
    int p = offsets[d] + atomicAdd(&cursor[d], 1);
    es[p] = src[e];
}

// ---------------- fused softmax + aggregation: one WAVE per dst node ----------------
// block = 256 threads = 4 waves = 4 nodes; lane owns channels {2*lane, 2*lane+1}
template<int H, bool ELU>
__global__ __launch_bounds__(256) void fused_agg(
    const int* __restrict__ offsets, const int* __restrict__ es,
    const float* __restrict__ s_src, const float* __restrict__ s_dst,
    const float* __restrict__ z, float* __restrict__ out)
{
    const int wid = threadIdx.x >> 6;
    const int lane = threadIdx.x & 63;
    const int n = blockIdx.x * 4 + wid;     // NN % 4 == 0, exact
    const int beg = offsets[n], end = offsets[n + 1];
    const int deg = end - beg;

    __shared__ float alpha_sh[4][128][H];
    __shared__ int   es_sh[4][128];
    __shared__ int   maxdeg;
    if (threadIdx.x == 0) maxdeg = 0;
    __syncthreads();
    if (lane == 0) atomicMax(&maxdeg, deg);
    __syncthreads();
    const int nch = (maxdeg + 127) >> 7;    // uniform across block -> safe barriers

    // wave-uniform dst-side scores
    float sdv[H];
    #pragma unroll
    for (int h = 0; h < H; ++h) sdv[h] = s_dst[(size_t)n * H + h];

    // ---- pass 1: per-head max (wave-local, shuffle reduce) ----
    float m[H];
    #pragma unroll
    for (int h = 0; h < H; ++h) m[h] = -INFINITY;
    for (int i = beg + lane; i < end; i += 64) {
        const int s = es[i];
        if (H == 4) {
            const float4 sv = *(const float4*)&s_src[(size_t)s * 4];
            const float svv[4] = {sv.x, sv.y, sv.z, sv.w};
            #pragma unroll
            for (int h = 0; h < 4; ++h) {
                float v = svv[h] + sdv[h];
                v = v > 0.f ? v : 0.01f * v;
                m[h] = fmaxf(m[h], v);
            }
        } else {
            float v = s_src[s] + sdv[0];
            v = v > 0.f ? v : 0.01f * v;
            m[0] = fmaxf(m[0], v);
        }
    }
    #pragma unroll
    for (int h = 0; h < H; ++h)
        #pragma unroll
        for (int off = 1; off < 64; off <<= 1)
            m[h] = fmaxf(m[h], __shfl_xor(m[h], off, 64));

    // ---- pass 2: per-head sum of exp ----
    float ssum[H];
    #pragma unroll
    for (int h = 0; h < H; ++h) ssum[h] = 0.f;
    for (int i = beg + lane; i < end; i += 64) {
        const int s = es[i];
        if (H == 4) {
            const float4 sv = *(const float4*)&s_src[(size_t)s * 4];
            const float svv[4] = {sv.x, sv.y, sv.z, sv.w};
            #pragma unroll
            for (int h = 0; h < 4; ++h) {
                float v = svv[h] + sdv[h];
                v = v > 0.f ? v : 0.01f * v;
                ssum[h] += __expf(v - m[h]);
            }
        } else {
            float v = s_src[s] + sdv[0];
            v = v > 0.f ? v : 0.01f * v;
            ssum[0] += __expf(v - m[0]);
        }
    }
    #pragma unroll
    for (int h = 0; h < H; ++h) {
        #pragma unroll
        for (int off = 1; off < 64; off <<= 1)
            ssum[h] += __shfl_xor(ssum[h], off, 64);
    }
    float inv[H];
    #pragma unroll
    for (int h = 0; h < H; ++h) inv[h] = 1.0f / fmaxf(ssum[h], 1e-9f);

    // ---- pass 3: chunked alpha + accumulate ----
    const int myh = (H == 4) ? (lane >> 4) : 0;
    float2 acc = make_float2(0.f, 0.f);
    for (int k = 0; k < nch; ++k) {
        const int base = beg + k * 128;
        int cnt = end - base;
        cnt = cnt < 0 ? 0 : (cnt > 128 ? 128 : cnt);
        for (int idx = lane; idx < cnt; idx += 64) {
            const int s = es[base + idx];
            es_sh[wid][idx] = s;
            if (H == 4) {
                const float4 sv = *(const float4*)&s_src[(size_t)s * 4];
                const float svv[4] = {sv.x, sv.y, sv.z, sv.w};
                float a4[4];
                #pragma unroll
                for (int h = 0; h < 4; ++h) {
                    float v = svv[h] + sdv[h];
                    v = v > 0.f ? v : 0.01f * v;
                    a4[h] = __expf(v - m[h]) * inv[h];
                }
                *(float4*)&alpha_sh[wid][idx][0] = make_float4(a4[0], a4[1], a4[2], a4[3]);
            } else {
                float v = s_src[s] + sdv[0];
                v = v > 0.f ? v : 0.01f * v;
                alpha_sh[wid][idx][0] = __expf(v - m[0]) * inv[0];
            }
        }
        __syncthreads();
        int j = 0;
        for (; j + 2 <= cnt; j += 2) {
            const int s0 = es_sh[wid][j],     s1 = es_sh[wid][j + 1];
            const float a0 = alpha_sh[wid][j][myh], a1 = alpha_sh[wid][j + 1][myh];
            const float2 z0 = *(const float2*)&z[(size_t)s0 * CH + lane * 2];
            const float2 z1 = *(const float2*)&z[(size_t)s1 * CH + lane * 2];
            acc.x = fmaf(a0, z0.x, acc.x); acc.y = fmaf(a0, z0.y, acc.y);
            acc.x = fmaf(a1, z1.x, acc.x); acc.y = fmaf(a1, z1.y, acc.y);
        }
        if (j < cnt) {
            const int s0 = es_sh[wid][j];
            const float a0 = alpha_sh[wid][j][myh];
            const float2 z0 = *(const float2*)&z[(size_t)s0 * CH + lane * 2];
            acc.x = fmaf(a0, z0.x, acc.x); acc.y = fmaf(a0, z0.y, acc.y);
        }
        __syncthreads();
    }

    if (ELU) {
        acc.x = acc.x > 0.f ? acc.x : expm1f(acc.x);
        acc.y = acc.y > 0.f ? acc.y : expm1f(acc.y);
    }
    *(float2*)&out[(size_t)n * CH + lane * 2] = acc;
}

// ---------------- host ----------------
extern "C" void kernel_launch(void* const* d_in, const int* in_sizes, int n_in,
                              void* d_out, int out_size, void* d_ws, size_t ws_size,
                              hipStream_t stream)
{
    const float* h   = (const float*)d_in[0];
    const float* W1  = (const float*)d_in[1];
    const float* a1  = (const float*)d_in[2];
    const float* W2  = (const float*)d_in[3];
    const float* a2  = (const float*)d_in[4];
    const int*   src = (const int*)d_in[5];
    const int*   dst = (const int*)d_in[6];
    float* out = (float*)d_out;

    char* ws = (char*)d_ws;
    unsigned short* Bthi1 = (unsigned short*)(ws + 0);        // 196608 B
    unsigned short* Btlo1 = (unsigned short*)(ws + 196608);   // 196608 B
    float* z       = (float*)(ws + 393216);                   // 25.6 MB
    float* h1      = (float*)(ws + 25993216);                 // 25.6 MB
    float* ss      = (float*)(ws + 51593216);                 // 800 KB (s_src, both layers)
    float* sd      = (float*)(ws + 52393216);                 // 800 KB (s_dst)
    int*   counts  = (int*)  (ws + 53193216);                 // 200 KB
    int*   exc     = (int*)  (ws + 53393216);                 // 200 KB
    int*   bsum    = (int*)  (ws + 53593216);                 // 1 KB
    int*   bexc    = (int*)  (ws + 53594240);                 // 1 KB
    int*   offsets = (int*)  (ws + 53595264);                 // 200 KB (+4)
    int*   cursor  = (int*)  (ws + 53795344);                 // 200 KB
    int*   es      = (int*)  (ws + 53995344);                 // 3.2 MB
    unsigned short* Bthi2 = (unsigned short*)(ws + 57195344); // 32 KB
    unsigned short* Btlo2 = (unsigned short*)(ws + 57228112); // 32 KB

    const int EB = 256;
    const int egrid = (NE + EB - 1) / EB;
    const int ggrid = (NN + GBM - 1) / GBM;
    const int sgrid = (NN + 3) / 4;
    const int agrid = NN / 4;

    // --- CSR build (shared by both layers) ---
    hipMemsetAsync(counts, 0, NN * sizeof(int), stream);
    hipMemsetAsync(cursor, 0, NN * sizeof(int), stream);
    count_k<<<egrid, EB, 0, stream>>>(dst, counts);
    scan1<<<NBLK, 256, 0, stream>>>(counts, exc, bsum);
    scan2<<<1, 256, 0, stream>>>(bsum, bexc);
    scan3<<<NBLK, 256, 0, stream>>>(exc, bexc, offsets);
    scatter_es<<<egrid, EB, 0, stream>>>(src, dst, offsets, cursor, es);

    // --- weight prep (split bf16, transposed) ---
    prep_b1<<<(CH * IND + 255) / 256, 256, 0, stream>>>(W1, Bthi1, Btlo1);
    prep_b2<<<(CH * CH + 255) / 256, 256, 0, stream>>>(W2, Bthi2, Btlo2);

    // --- layer 1 ---
    gemm_split<<<ggrid, 256, 0, stream>>>(h, Bthi1, Btlo1, z, NN, IND);
    compute_s_w<4><<<sgrid, 256, 0, stream>>>(z, a1, ss, sd);
    fused_agg<4, true><<<agrid, 256, 0, stream>>>(offsets, es, ss, sd, z, h1);

    // --- layer 2 ---
    gemm_split<<<ggrid, 256, 0, stream>>>(h1, Bthi2, Btlo2, z, NN, CH);
    compute_s_w<1><<<sgrid, 256, 0, stream>>>(z, a2, ss, sd);
    fused_agg<1, false><<<agrid, 256, 0, stream>>>(offsets, es, ss, sd, z, out);
}